// Round 8
// baseline (251.408 us; speedup 1.0000x reference)
//
#include <hip/hip_runtime.h>
#include <hip/hip_bf16.h>
#include <math.h>

// Problem dims: B=16,S=512,W=5,D=200,H=768  (BS=8192 rows, M1=40960 word-rows)
// Math: Ct = W2@attn_W^T; T = tanh(E@W1+b1); P = x@C; alpha = softmax(T_w.P+mask)
//       S = sum_w alpha_w T_w; H = x + S@W2 + b2; out = LN(H)*gamma+beta
// R8: GEMMs consume fp32 A/B operands directly (in-register bf16 cvt +
//     ds_write_b128 into the same XOR-swizzled LDS layout) -- removes the
//     prep round-trips for E (54MB) and x (38MB) and the W cvts; prep is now
//     just the two weight transposes. E's K-pad (200->256) is done by
//     zero-filling LDS chunks with k>=200 (200 = 25 full 8-elem chunks).

typedef __attribute__((ext_vector_type(8))) short bf16x8;
typedef __attribute__((ext_vector_type(4))) float f32x4;

__device__ __forceinline__ unsigned short f2bf_bits(float f) {
    __hip_bfloat16 h = __float2bfloat16(f);
    return *reinterpret_cast<unsigned short*>(&h);
}
__device__ __forceinline__ float bf_bits2f(unsigned short u) {
    union { unsigned int i; float f; } v; v.i = ((unsigned int)u) << 16; return v.f;
}
__device__ __forceinline__ float tanh_fast(float x) {
    float xc = fminf(fmaxf(x, -9.f), 9.f);
    float t  = __expf(2.f * xc);
    return (t - 1.f) * __builtin_amdgcn_rcpf(t + 1.f);
}

__device__ __forceinline__ void async_cp16(const void* g, void* lds) {
#if __has_builtin(__builtin_amdgcn_global_load_lds)
    auto gp = (const __attribute__((address_space(1))) unsigned int*)g;
    auto lp = (__attribute__((address_space(3))) unsigned int*)lds;
    __builtin_amdgcn_global_load_lds(gp, lp, 16, 0, 0);
#else
    *(uint4*)lds = *(const uint4*)g;
#endif
}

__device__ __forceinline__ void cvt8_store(const float* src, bool valid, unsigned short* lds) {
    float4 v0 = make_float4(0.f, 0.f, 0.f, 0.f), v1 = v0;
    if (valid) { v0 = *(const float4*)src; v1 = *(const float4*)(src + 4); }
    alignas(16) unsigned short h[8] = {
        f2bf_bits(v0.x), f2bf_bits(v0.y), f2bf_bits(v0.z), f2bf_bits(v0.w),
        f2bf_bits(v1.x), f2bf_bits(v1.y), f2bf_bits(v1.z), f2bf_bits(v1.w)};
    *(uint4*)lds = *(const uint4*)h;
}

// ---------- MFMA bf16 GEMM: D = A[M,K] @ Bt[N,K]^T (+bias)(tanh)(+resid) ----------
// A/B may be fp32 (converted during staging; KASRC = real fp32 K-cols of A,
// zero-fill beyond). 1D grid (GX*gridY); M%128==0; N,K compile-time; K%64==0.
template<bool HAS_BIAS, bool TANH_ACT, bool RESID, bool OUT_BF16,
         bool A_F32, bool B_F32, int N, int K, int KASRC, int GX>
__global__ __launch_bounds__(256) void mfma_gemm(
    const void* __restrict__ A,
    const void* __restrict__ Bt,
    const float* __restrict__ bias,
    const float* __restrict__ resid,
    void* __restrict__ outp)
{
    __shared__ __align__(16) unsigned char smem[32768];
    unsigned short* As = (unsigned short*)smem;            // 128 rows x 64 k = 16KB
    unsigned short* Bs = (unsigned short*)(smem + 16384);  // 16KB

    int bx, by;
    {
        const int total = gridDim.x;
        const int per_xcd = total >> 3;
        if ((total & 7) == 0 && (per_xcd % GX) == 0) {
            int xcd = blockIdx.x & 7, idx = blockIdx.x >> 3;
            int lin = xcd * per_xcd + idx;
            by = lin / GX; bx = lin % GX;
        } else { by = blockIdx.x / GX; bx = blockIdx.x % GX; }
    }
    const int m0 = by * 128;
    const int n0 = bx * 128;

    const int tid  = threadIdx.x;
    const int lane = tid & 63;
    const int wave = tid >> 6;          // 4 waves, 2x2
    const int wm   = wave & 1;
    const int wn   = wave >> 1;

    // XOR-swizzled staging: chunk (r,kc) at slot s = kc ^ (r&7); permute the
    // SOURCE per lane (kc = slot ^ rsub) so the LDS dest stays base+lane*16.
    const int rsub = lane >> 3;          // 0..7
    const int slot = lane & 7;           // 0..7
    const int kc   = slot ^ rsub;        // logical k-chunk this lane fetches

    const __hip_bfloat16* gA = (const __hip_bfloat16*)A  + (size_t)(m0 + wave * 32 + rsub) * K + kc * 8;
    const __hip_bfloat16* gB = (const __hip_bfloat16*)Bt + (size_t)(n0 + wave * 32 + rsub) * K + kc * 8;
    const float* gAf = (const float*)A  + (size_t)(m0 + wave * 32 + rsub) * KASRC + kc * 8;
    const float* gBf = (const float*)Bt + (size_t)(n0 + wave * 32 + rsub) * K + kc * 8;
    unsigned short* lA = As + wave * 2048 + lane * 8;
    unsigned short* lB = Bs + wave * 2048 + lane * 8;

    const int row16 = lane & 15;
    const int kq    = lane >> 4;         // 0..3

    f32x4 acc[4][4];
#pragma unroll
    for (int i = 0; i < 4; i++)
#pragma unroll
        for (int j = 0; j < 4; j++) acc[i][j] = (f32x4){0.f, 0.f, 0.f, 0.f};

    for (int k0 = 0; k0 < K; k0 += 64) {
        const bool avalid = !A_F32 || (k0 + kc * 8 < KASRC);  // KASRC%8==0 -> chunk-level
#pragma unroll
        for (int i = 0; i < 4; i++) {
            if (A_F32) cvt8_store(gAf + (size_t)(8 * i) * KASRC, avalid, lA + i * 512);
            else       async_cp16(gA + (size_t)(8 * i) * K, lA + i * 512);
            if (B_F32) cvt8_store(gBf + (size_t)(8 * i) * K, true, lB + i * 512);
            else       async_cp16(gB + (size_t)(8 * i) * K, lB + i * 512);
        }
        gA += 64; gB += 64; gAf += 64; gBf += 64;
        __syncthreads();

        bf16x8 af[2][4], bg[2][4];
#pragma unroll
        for (int kh = 0; kh < 2; kh++) {
#pragma unroll
            for (int mi = 0; mi < 4; mi++) {
                const int r = wm * 64 + mi * 16 + row16;
                const int s = (kh * 4 + kq) ^ (r & 7);
                af[kh][mi] = *(const bf16x8*)&As[r * 64 + s * 8];
            }
#pragma unroll
            for (int ni = 0; ni < 4; ni++) {
                const int r = wn * 64 + ni * 16 + row16;
                const int s = (kh * 4 + kq) ^ (r & 7);
                bg[kh][ni] = *(const bf16x8*)&Bs[r * 64 + s * 8];
            }
        }
#pragma unroll
        for (int kh = 0; kh < 2; kh++)
#pragma unroll
            for (int mi = 0; mi < 4; mi++)
#pragma unroll
                for (int ni = 0; ni < 4; ni++)
                    acc[mi][ni] = __builtin_amdgcn_mfma_f32_16x16x32_bf16(
                        af[kh][mi], bg[kh][ni], acc[mi][ni], 0, 0, 0);
        __syncthreads();
    }

    // ---- epilogue: repack C-tile through LDS, coalesced 16B stores ----
    if (OUT_BF16) {
        unsigned short* rep = (unsigned short*)smem;   // 128x128 bf16 = 32KB
#pragma unroll
        for (int ni = 0; ni < 4; ni++) {
            const int c = wn * 64 + ni * 16 + row16;
            float bcol = HAS_BIAS ? bias[n0 + c] : 0.f;
#pragma unroll
            for (int mi = 0; mi < 4; mi++)
#pragma unroll
                for (int r = 0; r < 4; r++) {
                    const int rr = wm * 64 + mi * 16 + kq * 4 + r;
                    float v = acc[mi][ni][r];
                    if (HAS_BIAS) v += bcol;
                    if (TANH_ACT) v = tanh_fast(v);
                    rep[rr * 128 + c] = f2bf_bits(v);
                }
        }
        __syncthreads();
#pragma unroll
        for (int p = 0; p < 8; p++) {
            const int lin = p * 256 + tid;     // 128 rows x 16 chunks of 8
            const int row = lin >> 4;
            const int c8  = lin & 15;
            uint4 d = *(const uint4*)&rep[row * 128 + c8 * 8];
            *(uint4*)((__hip_bfloat16*)outp + (size_t)(m0 + row) * N + n0 + c8 * 8) = d;
        }
    } else {
        float* rep = (float*)smem;             // 64x128 f32 = 32KB per half
#pragma unroll
        for (int h = 0; h < 2; h++) {
            if (wm == h) {
#pragma unroll
                for (int ni = 0; ni < 4; ni++) {
                    const int c = wn * 64 + ni * 16 + row16;
                    float bcol = HAS_BIAS ? bias[n0 + c] : 0.f;
#pragma unroll
                    for (int mi = 0; mi < 4; mi++)
#pragma unroll
                        for (int r = 0; r < 4; r++) {
                            const int rr = mi * 16 + kq * 4 + r;   // 0..63
                            float v = acc[mi][ni][r];
                            if (HAS_BIAS) v += bcol;
                            if (TANH_ACT) v = tanh_fast(v);
                            rep[rr * 128 + c] = v;
                        }
                }
            }
            __syncthreads();
#pragma unroll
            for (int p = 0; p < 8; p++) {
                const int lin = p * 256 + tid;   // 64 rows x 32 float4
                const int row = lin >> 5;
                const int c4  = lin & 31;
                float4 v = *(const float4*)&rep[row * 128 + c4 * 4];
                const int grow = m0 + h * 64 + row;
                if (RESID) {
                    float4 rv = *(const float4*)&resid[(size_t)grow * N + n0 + c4 * 4];
                    v.x += rv.x; v.y += rv.y; v.z += rv.z; v.w += rv.w;
                }
                *(float4*)((float*)outp + (size_t)grow * N + n0 + c4 * 4) = v;
            }
            __syncthreads();
        }
    }
}

// ---------- prep: transpose W1 -> [768,256] (rows 200.. zero), W2 -> [768,768] ----------
__global__ __launch_bounds__(256) void prep_kernel(
    const float* __restrict__ W1, __hip_bfloat16* __restrict__ W1Tb,
    const float* __restrict__ W2, __hip_bfloat16* __restrict__ W2Tb)
{
    __shared__ float tile[32][33];
    const int b = blockIdx.x, tid = threadIdx.x;
    const float* in; __hip_bfloat16* outb; int R, C, Rpad, t;
    if (b < 192) { t = b;       in = W1; outb = W1Tb; R = 200; C = 768; Rpad = 256; }
    else         { t = b - 192; in = W2; outb = W2Tb; R = 768; C = 768; Rpad = 768; }
    const int c0 = (t % 24) * 32, r0 = (t / 24) * 32;
    const int xx = tid & 31, yy = tid >> 5;       // (32,8)
#pragma unroll
    for (int i = 0; i < 32; i += 8) {
        int r = r0 + yy + i;
        tile[yy + i][xx] = (r < R) ? in[(size_t)r * C + c0 + xx] : 0.f;
    }
    __syncthreads();
#pragma unroll
    for (int i = 0; i < 32; i += 8)
        outb[(size_t)(c0 + yy + i) * Rpad + r0 + xx] = __float2bfloat16(tile[xx][yy + i]);
}

// ---------- attention: wave per (b,s) row; P aliases S ----------
__global__ __launch_bounds__(256) void attn_kernel(
    const __hip_bfloat16* __restrict__ T,
    const __hip_bfloat16* P,
    const int* __restrict__ mask,
    __hip_bfloat16* S)
{
    const int lane = threadIdx.x & 63;
    const int wave = threadIdx.x >> 6;
    const int r    = blockIdx.x * 4 + wave;
    const int base = lane * 12;

    float pv[12];
    {
        const ushort4* pp = (const ushort4*)((const unsigned short*)P + (size_t)r * 768 + base);
        ushort4 u0 = pp[0], u1 = pp[1], u2 = pp[2];
        unsigned short us[12] = {u0.x,u0.y,u0.z,u0.w, u1.x,u1.y,u1.z,u1.w, u2.x,u2.y,u2.z,u2.w};
#pragma unroll
        for (int j = 0; j < 12; j++) pv[j] = bf_bits2f(us[j]);
    }
    float tv[5][12], part[5];
#pragma unroll
    for (int w = 0; w < 5; w++) {
        const ushort4* tp = (const ushort4*)((const unsigned short*)T + ((size_t)r * 5 + w) * 768 + base);
        ushort4 u0 = tp[0], u1 = tp[1], u2 = tp[2];
        unsigned short us[12] = {u0.x,u0.y,u0.z,u0.w, u1.x,u1.y,u1.z,u1.w, u2.x,u2.y,u2.z,u2.w};
        float s = 0.f;
#pragma unroll
        for (int j = 0; j < 12; j++) { tv[w][j] = bf_bits2f(us[j]); s += tv[w][j] * pv[j]; }
        part[w] = s;
    }
#pragma unroll
    for (int off = 32; off > 0; off >>= 1)
#pragma unroll
        for (int w = 0; w < 5; w++)
            part[w] += __shfl_xor(part[w], off, 64);

    float logit[5], mx = -1e30f;
#pragma unroll
    for (int w = 0; w < 5; w++) {
        float m = (float)mask[(size_t)r * 5 + w];
        logit[w] = part[w] - 10000.0f * (1.0f - m);
        mx = fmaxf(mx, logit[w]);
    }
    float se = 0.f;
#pragma unroll
    for (int w = 0; w < 5; w++) { logit[w] = expf(logit[w] - mx); se += logit[w]; }
    const float inv = 1.0f / se;

    unsigned short os[12];
#pragma unroll
    for (int j = 0; j < 12; j++) {
        float s = 0.f;
#pragma unroll
        for (int w = 0; w < 5; w++) s += logit[w] * tv[w][j];
        os[j] = f2bf_bits(s * inv);
    }
    ushort4* sp = (ushort4*)((unsigned short*)S + (size_t)r * 768 + base);
    sp[0] = make_ushort4(os[0], os[1], os[2],  os[3]);
    sp[1] = make_ushort4(os[4], os[5], os[6],  os[7]);
    sp[2] = make_ushort4(os[8], os[9], os[10], os[11]);
}

// ---------- LayerNorm over H=768, wave per row ----------
__global__ __launch_bounds__(256) void ln_kernel(
    const float* __restrict__ Hbuf, const float* __restrict__ gamma,
    const float* __restrict__ beta, float* __restrict__ out)
{
    const int lane = threadIdx.x & 63;
    const int wave = threadIdx.x >> 6;
    const int r    = blockIdx.x * 4 + wave;
    const float* hr = Hbuf + (size_t)r * 768 + lane * 12;

    float v[12];
    {
        float4 a = *(const float4*)(hr);
        float4 b = *(const float4*)(hr + 4);
        float4 c = *(const float4*)(hr + 8);
        v[0]=a.x; v[1]=a.y; v[2]=a.z; v[3]=a.w;
        v[4]=b.x; v[5]=b.y; v[6]=b.z; v[7]=b.w;
        v[8]=c.x; v[9]=c.y; v[10]=c.z; v[11]=c.w;
    }
    float s = 0.f;
#pragma unroll
    for (int j = 0; j < 12; j++) s += v[j];
#pragma unroll
    for (int off = 32; off > 0; off >>= 1) s += __shfl_xor(s, off, 64);
    const float mu = s * (1.f / 768.f);
    float vs = 0.f;
#pragma unroll
    for (int j = 0; j < 12; j++) { float d = v[j] - mu; vs += d * d; }
#pragma unroll
    for (int off = 32; off > 0; off >>= 1) vs += __shfl_xor(vs, off, 64);
    const float rs = rsqrtf(vs * (1.f / 768.f) + 1e-12f);

    float o[12];
#pragma unroll
    for (int j = 0; j < 12; j++) {
        int h = lane * 12 + j;
        o[j] = (v[j] - mu) * rs * gamma[h] + beta[h];
    }
    float* orow = out + (size_t)r * 768 + lane * 12;
    *(float4*)(orow)     = make_float4(o[0], o[1], o[2],  o[3]);
    *(float4*)(orow + 4) = make_float4(o[4], o[5], o[6],  o[7]);
    *(float4*)(orow + 8) = make_float4(o[8], o[9], o[10], o[11]);
}

extern "C" void kernel_launch(void* const* d_in, const int* in_sizes, int n_in,
                              void* d_out, int out_size, void* d_ws, size_t ws_size,
                              hipStream_t stream)
{
    const float* x      = (const float*)d_in[0];
    const float* E      = (const float*)d_in[1];
    const int*   mask   = (const int*)d_in[2];
    const float* W1     = (const float*)d_in[3];
    const float* b1     = (const float*)d_in[4];
    const float* W2     = (const float*)d_in[5];
    const float* b2     = (const float*)d_in[6];
    const float* attn_W = (const float*)d_in[7];
    const float* gamma  = (const float*)d_in[8];
    const float* beta   = (const float*)d_in[9];
    float* out = (float*)d_out;

    const int BS = 8192, H = 768, M1 = 40960, KP = 256;

    char* p = (char*)d_ws;
    auto alloc = [&](size_t bytes) { char* q = p; p += (bytes + 255) & ~(size_t)255; return q; };
    __hip_bfloat16* W2Tb  = (__hip_bfloat16*)alloc((size_t)H * H * 2);
    __hip_bfloat16* Ctb   = (__hip_bfloat16*)alloc((size_t)H * H * 2);
    __hip_bfloat16* W1Tb  = (__hip_bfloat16*)alloc((size_t)H * KP * 2);
    __hip_bfloat16* Tb    = (__hip_bfloat16*)alloc((size_t)M1 * H * 2);    // 62.92 MB
    __hip_bfloat16* Pb    = (__hip_bfloat16*)alloc((size_t)BS * H * 2);    // 12.58 MB
    float* Hb = (float*)Tb;              // alias: Tb dead after attn
    __hip_bfloat16* Sb = Pb;             // alias: same-wave read-then-write

    // --- prep: the two weight transposes only (E/x/W2/attn consumed fp32 by GEMMs)
    prep_kernel<<<768, 256, 0, stream>>>(W1, W1Tb, W2, W2Tb);

    // Ct = W2 @ attn_W^T   (both operands fp32, 36 blocks -> identity decode)
    mfma_gemm<false, false, false, true, true, true, 768, 768, 768, 6>
        <<<36, 256, 0, stream>>>(W2, attn_W, nullptr, nullptr, Ctb);
    // T = tanh(E @ W1 + b1)   (A = fp32 E, KASRC=200, zero-padded to K=256)
    mfma_gemm<true, true, false, true, true, false, 768, 256, 200, 6>
        <<<1920, 256, 0, stream>>>(E, W1Tb, b1, nullptr, Tb);
    // P = x @ C   (A = fp32 x)
    mfma_gemm<false, false, false, true, true, false, 768, 768, 768, 6>
        <<<384, 256, 0, stream>>>(x, Ctb, nullptr, nullptr, Pb);
    // attention -> S
    attn_kernel<<<BS / 4, 256, 0, stream>>>(Tb, Pb, mask, Sb);
    // H = x + S @ W2 + b2   (A = bf16 S)
    mfma_gemm<true, false, true, false, false, false, 768, 768, 768, 6>
        <<<384, 256, 0, stream>>>(Sb, W2Tb, b2, x, Hb);
    // out = LN(H)*gamma + beta
    ln_kernel<<<BS / 4, 256, 0, stream>>>(Hb, gamma, beta, out);
}

// Round 9
// 216.457 us; speedup vs baseline: 1.1615x; 1.1615x over previous
//
#include <hip/hip_runtime.h>
#include <hip/hip_bf16.h>
#include <math.h>

// Problem dims: B=16,S=512,W=5,D=200,H=768  (BS=8192 rows, M1=40960 word-rows)
// Math: Ct = W2@attn_W^T; T = tanh(E@W1+b1); P = x@C; alpha = softmax(T_w.P+mask)
//       S = sum_w alpha_w T_w; H = x + S@W2 + b2; out = LN(H)*gamma+beta
// R9: revert R8's fp32-direct staging (sync load->cvt->ds_write chain killed the
//     async pipeline: T-GEMM 41->60us, occupancy 25->16%). Back to R7 (bf16 prep
//     + global_load_lds). New: (a) KREAL tail-skip -- k in [224,256) of Eb/W1T is
//     zeros, so the last K-iter runs only kh=0 (16 fewer MFMA + 8 fewer ds_read
//     per wave, compile-time); (b) Ct-GEMM fused into the T launch as blocks
//     1920..1955 (removes a 36-block kernel that idled 220 CUs; 6 launches).

typedef __attribute__((ext_vector_type(8))) short bf16x8;
typedef __attribute__((ext_vector_type(4))) float f32x4;

__device__ __forceinline__ unsigned short f2bf_bits(float f) {
    __hip_bfloat16 h = __float2bfloat16(f);
    return *reinterpret_cast<unsigned short*>(&h);
}
__device__ __forceinline__ float bf_bits2f(unsigned short u) {
    union { unsigned int i; float f; } v; v.i = ((unsigned int)u) << 16; return v.f;
}
__device__ __forceinline__ float tanh_fast(float x) {
    float xc = fminf(fmaxf(x, -9.f), 9.f);
    float t  = __expf(2.f * xc);
    return (t - 1.f) * __builtin_amdgcn_rcpf(t + 1.f);
}

__device__ __forceinline__ void async_cp16(const void* g, void* lds) {
#if __has_builtin(__builtin_amdgcn_global_load_lds)
    auto gp = (const __attribute__((address_space(1))) unsigned int*)g;
    auto lp = (__attribute__((address_space(3))) unsigned int*)lds;
    __builtin_amdgcn_global_load_lds(gp, lp, 16, 0, 0);
#else
    *(uint4*)lds = *(const uint4*)g;
#endif
}

// ---------- MFMA bf16 GEMM body: D = A[M,K] @ Bt[N,K]^T (+bias)(tanh)(+resid) ----
// XOR-swizzled LDS (slot = kc ^ (row&7)); BK=64; K%64==0; KREAL = valid k cols
// (k >= KREAL are zeros in A and Bt -> kh skipped at compile time).
template<bool HAS_BIAS, bool TANH_ACT, bool RESID, bool OUT_BF16, int N, int K, int KREAL>
__device__ __forceinline__ void gemm_body(
    const __hip_bfloat16* __restrict__ A,
    const __hip_bfloat16* __restrict__ Bt,
    const float* __restrict__ bias,
    const float* __restrict__ resid,
    void* __restrict__ outp,
    int m0, int n0, unsigned char* smem)
{
    unsigned short* As = (unsigned short*)smem;            // 128 rows x 64 k = 16KB
    unsigned short* Bs = (unsigned short*)(smem + 16384);  // 16KB

    const int tid  = threadIdx.x;
    const int lane = tid & 63;
    const int wave = tid >> 6;          // 4 waves, 2x2
    const int wm   = wave & 1;
    const int wn   = wave >> 1;

    // staging: chunk (r,kc) lives at slot s = kc ^ (r&7); permute the SOURCE per
    // lane (kc = slot ^ rsub) so the LDS dest stays base+lane*16 (HW constraint).
    const int rsub = lane >> 3;          // 0..7
    const int slot = lane & 7;           // 0..7
    const int kc   = slot ^ rsub;        // logical k-chunk this lane fetches
    const __hip_bfloat16* gA = A  + (size_t)(m0 + wave * 32 + rsub) * K + kc * 8;
    const __hip_bfloat16* gB = Bt + (size_t)(n0 + wave * 32 + rsub) * K + kc * 8;
    unsigned short* lA = As + wave * 2048 + lane * 8;
    unsigned short* lB = Bs + wave * 2048 + lane * 8;

    const int row16 = lane & 15;
    const int kq    = lane >> 4;         // 0..3

    f32x4 acc[4][4];
#pragma unroll
    for (int i = 0; i < 4; i++)
#pragma unroll
        for (int j = 0; j < 4; j++) acc[i][j] = (f32x4){0.f, 0.f, 0.f, 0.f};

#pragma unroll
    for (int k0 = 0; k0 < K; k0 += 64) {
#pragma unroll
        for (int i = 0; i < 4; i++) {
            async_cp16(gA + (size_t)(8 * i) * K, lA + i * 512);
            async_cp16(gB + (size_t)(8 * i) * K, lB + i * 512);
        }
        gA += 64; gB += 64;
        __syncthreads();

        const bool full = (k0 + 32 < KREAL);   // compile-time per unrolled iter

        bf16x8 af[2][4], bg[2][4];
#pragma unroll
        for (int mi = 0; mi < 4; mi++) {
            const int r = wm * 64 + mi * 16 + row16;
            af[0][mi] = *(const bf16x8*)&As[r * 64 + (kq ^ (r & 7)) * 8];
            if (full) af[1][mi] = *(const bf16x8*)&As[r * 64 + ((4 + kq) ^ (r & 7)) * 8];
        }
#pragma unroll
        for (int ni = 0; ni < 4; ni++) {
            const int r = wn * 64 + ni * 16 + row16;
            bg[0][ni] = *(const bf16x8*)&Bs[r * 64 + (kq ^ (r & 7)) * 8];
            if (full) bg[1][ni] = *(const bf16x8*)&Bs[r * 64 + ((4 + kq) ^ (r & 7)) * 8];
        }
#pragma unroll
        for (int mi = 0; mi < 4; mi++)
#pragma unroll
            for (int ni = 0; ni < 4; ni++)
                acc[mi][ni] = __builtin_amdgcn_mfma_f32_16x16x32_bf16(
                    af[0][mi], bg[0][ni], acc[mi][ni], 0, 0, 0);
        if (full) {
#pragma unroll
            for (int mi = 0; mi < 4; mi++)
#pragma unroll
                for (int ni = 0; ni < 4; ni++)
                    acc[mi][ni] = __builtin_amdgcn_mfma_f32_16x16x32_bf16(
                        af[1][mi], bg[1][ni], acc[mi][ni], 0, 0, 0);
        }
        __syncthreads();
    }

    // ---- epilogue: repack C-tile through LDS, coalesced 16B stores ----
    if (OUT_BF16) {
        unsigned short* rep = (unsigned short*)smem;   // 128x128 bf16 = 32KB
#pragma unroll
        for (int ni = 0; ni < 4; ni++) {
            const int c = wn * 64 + ni * 16 + row16;
            float bcol = HAS_BIAS ? bias[n0 + c] : 0.f;
#pragma unroll
            for (int mi = 0; mi < 4; mi++)
#pragma unroll
                for (int r = 0; r < 4; r++) {
                    const int rr = wm * 64 + mi * 16 + kq * 4 + r;
                    float v = acc[mi][ni][r];
                    if (HAS_BIAS) v += bcol;
                    if (TANH_ACT) v = tanh_fast(v);
                    rep[rr * 128 + c] = f2bf_bits(v);
                }
        }
        __syncthreads();
#pragma unroll
        for (int p = 0; p < 8; p++) {
            const int lin = p * 256 + tid;     // 128 rows x 16 chunks of 8
            const int row = lin >> 4;
            const int c8  = lin & 15;
            uint4 d = *(const uint4*)&rep[row * 128 + c8 * 8];
            *(uint4*)((__hip_bfloat16*)outp + (size_t)(m0 + row) * N + n0 + c8 * 8) = d;
        }
    } else {
        float* rep = (float*)smem;             // 64x128 f32 = 32KB per half
#pragma unroll
        for (int h = 0; h < 2; h++) {
            if (wm == h) {
#pragma unroll
                for (int ni = 0; ni < 4; ni++) {
                    const int c = wn * 64 + ni * 16 + row16;
                    float bcol = HAS_BIAS ? bias[n0 + c] : 0.f;
#pragma unroll
                    for (int mi = 0; mi < 4; mi++)
#pragma unroll
                        for (int r = 0; r < 4; r++) {
                            const int rr = mi * 16 + kq * 4 + r;   // 0..63
                            float v = acc[mi][ni][r];
                            if (HAS_BIAS) v += bcol;
                            if (TANH_ACT) v = tanh_fast(v);
                            rep[rr * 128 + c] = v;
                        }
                }
            }
            __syncthreads();
#pragma unroll
            for (int p = 0; p < 8; p++) {
                const int lin = p * 256 + tid;   // 64 rows x 32 float4
                const int row = lin >> 5;
                const int c4  = lin & 31;
                float4 v = *(const float4*)&rep[row * 128 + c4 * 4];
                const int grow = m0 + h * 64 + row;
                if (RESID) {
                    float4 rv = *(const float4*)&resid[(size_t)grow * N + n0 + c4 * 4];
                    v.x += rv.x; v.y += rv.y; v.z += rv.z; v.w += rv.w;
                }
                *(float4*)((float*)outp + (size_t)grow * N + n0 + c4 * 4) = v;
            }
            __syncthreads();
        }
    }
}

// ---------- standalone GEMM (P and H) with XCD swizzle ----------
template<bool HAS_BIAS, bool TANH_ACT, bool RESID, bool OUT_BF16, int N, int K, int GX>
__global__ __launch_bounds__(256) void mfma_gemm(
    const __hip_bfloat16* __restrict__ A,
    const __hip_bfloat16* __restrict__ Bt,
    const float* __restrict__ bias,
    const float* __restrict__ resid,
    void* __restrict__ outp)
{
    __shared__ __align__(16) unsigned char smem[32768];
    int bx, by;
    {
        const int total = gridDim.x;
        const int per_xcd = total >> 3;
        if ((total & 7) == 0 && (per_xcd % GX) == 0) {
            int xcd = blockIdx.x & 7, idx = blockIdx.x >> 3;
            int lin = xcd * per_xcd + idx;
            by = lin / GX; bx = lin % GX;
        } else { by = blockIdx.x / GX; bx = blockIdx.x % GX; }
    }
    gemm_body<HAS_BIAS, TANH_ACT, RESID, OUT_BF16, N, K, K>(
        A, Bt, bias, resid, outp, by * 128, bx * 128, smem);
}

// ---------- fused T-GEMM (blocks 0..1919) + Ct-GEMM (blocks 1920..1955) ----------
__global__ __launch_bounds__(256) void tct_kernel(
    const __hip_bfloat16* __restrict__ Eb,   const __hip_bfloat16* __restrict__ W1Tb,
    const float* __restrict__ b1,            __hip_bfloat16* __restrict__ Tb,
    const __hip_bfloat16* __restrict__ W2b,  const __hip_bfloat16* __restrict__ attnb,
    __hip_bfloat16* __restrict__ Ctb)
{
    __shared__ __align__(16) unsigned char smem[32768];
    if (blockIdx.x < 1920) {
        // XCD swizzle over 1920 blocks, GX=6 (240 per XCD, 240%6==0)
        const int xcd = blockIdx.x & 7, idx = blockIdx.x >> 3;
        const int lin = xcd * 240 + idx;
        gemm_body<true, true, false, true, 768, 256, 224>(
            Eb, W1Tb, b1, nullptr, Tb, (lin / 6) * 128, (lin % 6) * 128, smem);
    } else {
        const int id = blockIdx.x - 1920;    // 36 blocks
        gemm_body<false, false, false, true, 768, 768, 768>(
            W2b, attnb, nullptr, nullptr, Ctb, (id / 6) * 128, (id % 6) * 128, smem);
    }
}

// ---------- fused prep: cvt x/W2/attn_W, pad-cvt E (K->256), transpose W1/W2 ----------
__global__ __launch_bounds__(256) void prep_kernel(
    const float* __restrict__ x,  __hip_bfloat16* __restrict__ xb,
    const float* __restrict__ w2, __hip_bfloat16* __restrict__ w2b,
    const float* __restrict__ aw, __hip_bfloat16* __restrict__ awb,
    const float* __restrict__ E,  __hip_bfloat16* __restrict__ Eb,
    const float* __restrict__ W1, __hip_bfloat16* __restrict__ W1Tb,
    __hip_bfloat16* __restrict__ W2Tb)
{
    __shared__ float tile[32][33];
    const int b = blockIdx.x, tid = threadIdx.x;
    if (b < 6144 + 576 + 576) {                       // flat fp32->bf16 cvt
        const float* src; __hip_bfloat16* dst; long long i;
        if (b < 6144)      { src = x;  dst = xb;  i = (long long)b * 256 + tid; }
        else if (b < 6720) { src = w2; dst = w2b; i = (long long)(b - 6144) * 256 + tid; }
        else               { src = aw; dst = awb; i = (long long)(b - 6720) * 256 + tid; }
        float4 v = ((const float4*)src)[i];
        ((ushort4*)dst)[i] = make_ushort4(f2bf_bits(v.x), f2bf_bits(v.y), f2bf_bits(v.z), f2bf_bits(v.w));
    } else if (b < 7296 + 10240) {                    // E [40960,200] -> [40960,256]
        const int lane = tid & 63, wave = tid >> 6;
        const long long row = (long long)(b - 7296) * 4 + wave;
        const int k = lane * 4;
        float4 v = make_float4(0.f, 0.f, 0.f, 0.f);
        if (k < 200) v = *(const float4*)&E[row * 200 + k];   // k<=196 in-bounds
        *(ushort4*)&Eb[row * 256 + k] =
            make_ushort4(f2bf_bits(v.x), f2bf_bits(v.y), f2bf_bits(v.z), f2bf_bits(v.w));
    } else {                                          // transposes, (32,8) tiles
        const float* in; __hip_bfloat16* outb; int R, C, Rpad, t;
        if (b < 17536 + 192) { t = b - 17536; in = W1; outb = W1Tb; R = 200; C = 768; Rpad = 256; }
        else                 { t = b - 17728; in = w2; outb = W2Tb; R = 768; C = 768; Rpad = 768; }
        const int c0 = (t % 24) * 32, r0 = (t / 24) * 32;
        const int xx = tid & 31, yy = tid >> 5;       // (32,8)
#pragma unroll
        for (int i = 0; i < 32; i += 8) {
            int r = r0 + yy + i;
            tile[yy + i][xx] = (r < R) ? in[(size_t)r * C + c0 + xx] : 0.f;
        }
        __syncthreads();
#pragma unroll
        for (int i = 0; i < 32; i += 8)
            outb[(size_t)(c0 + yy + i) * Rpad + r0 + xx] = __float2bfloat16(tile[xx][yy + i]);
    }
}

// ---------- attention: wave per (b,s) row; P aliases S ----------
__global__ __launch_bounds__(256) void attn_kernel(
    const __hip_bfloat16* __restrict__ T,
    const __hip_bfloat16* P,
    const int* __restrict__ mask,
    __hip_bfloat16* S)
{
    const int lane = threadIdx.x & 63;
    const int wave = threadIdx.x >> 6;
    const int r    = blockIdx.x * 4 + wave;
    const int base = lane * 12;

    float pv[12];
    {
        const ushort4* pp = (const ushort4*)((const unsigned short*)P + (size_t)r * 768 + base);
        ushort4 u0 = pp[0], u1 = pp[1], u2 = pp[2];
        unsigned short us[12] = {u0.x,u0.y,u0.z,u0.w, u1.x,u1.y,u1.z,u1.w, u2.x,u2.y,u2.z,u2.w};
#pragma unroll
        for (int j = 0; j < 12; j++) pv[j] = bf_bits2f(us[j]);
    }
    float tv[5][12], part[5];
#pragma unroll
    for (int w = 0; w < 5; w++) {
        const ushort4* tp = (const ushort4*)((const unsigned short*)T + ((size_t)r * 5 + w) * 768 + base);
        ushort4 u0 = tp[0], u1 = tp[1], u2 = tp[2];
        unsigned short us[12] = {u0.x,u0.y,u0.z,u0.w, u1.x,u1.y,u1.z,u1.w, u2.x,u2.y,u2.z,u2.w};
        float s = 0.f;
#pragma unroll
        for (int j = 0; j < 12; j++) { tv[w][j] = bf_bits2f(us[j]); s += tv[w][j] * pv[j]; }
        part[w] = s;
    }
#pragma unroll
    for (int off = 32; off > 0; off >>= 1)
#pragma unroll
        for (int w = 0; w < 5; w++)
            part[w] += __shfl_xor(part[w], off, 64);

    float logit[5], mx = -1e30f;
#pragma unroll
    for (int w = 0; w < 5; w++) {
        float m = (float)mask[(size_t)r * 5 + w];
        logit[w] = part[w] - 10000.0f * (1.0f - m);
        mx = fmaxf(mx, logit[w]);
    }
    float se = 0.f;
#pragma unroll
    for (int w = 0; w < 5; w++) { logit[w] = expf(logit[w] - mx); se += logit[w]; }
    const float inv = 1.0f / se;

    unsigned short os[12];
#pragma unroll
    for (int j = 0; j < 12; j++) {
        float s = 0.f;
#pragma unroll
        for (int w = 0; w < 5; w++) s += logit[w] * tv[w][j];
        os[j] = f2bf_bits(s * inv);
    }
    ushort4* sp = (ushort4*)((unsigned short*)S + (size_t)r * 768 + base);
    sp[0] = make_ushort4(os[0], os[1], os[2],  os[3]);
    sp[1] = make_ushort4(os[4], os[5], os[6],  os[7]);
    sp[2] = make_ushort4(os[8], os[9], os[10], os[11]);
}

// ---------- LayerNorm over H=768, wave per row ----------
__global__ __launch_bounds__(256) void ln_kernel(
    const float* __restrict__ Hbuf, const float* __restrict__ gamma,
    const float* __restrict__ beta, float* __restrict__ out)
{
    const int lane = threadIdx.x & 63;
    const int wave = threadIdx.x >> 6;
    const int r    = blockIdx.x * 4 + wave;
    const float* hr = Hbuf + (size_t)r * 768 + lane * 12;

    float v[12];
    {
        float4 a = *(const float4*)(hr);
        float4 b = *(const float4*)(hr + 4);
        float4 c = *(const float4*)(hr + 8);
        v[0]=a.x; v[1]=a.y; v[2]=a.z; v[3]=a.w;
        v[4]=b.x; v[5]=b.y; v[6]=b.z; v[7]=b.w;
        v[8]=c.x; v[9]=c.y; v[10]=c.z; v[11]=c.w;
    }
    float s = 0.f;
#pragma unroll
    for (int j = 0; j < 12; j++) s += v[j];
#pragma unroll
    for (int off = 32; off > 0; off >>= 1) s += __shfl_xor(s, off, 64);
    const float mu = s * (1.f / 768.f);
    float vs = 0.f;
#pragma unroll
    for (int j = 0; j < 12; j++) { float d = v[j] - mu; vs += d * d; }
#pragma unroll
    for (int off = 32; off > 0; off >>= 1) vs += __shfl_xor(vs, off, 64);
    const float rs = rsqrtf(vs * (1.f / 768.f) + 1e-12f);

    float o[12];
#pragma unroll
    for (int j = 0; j < 12; j++) {
        int h = lane * 12 + j;
        o[j] = (v[j] - mu) * rs * gamma[h] + beta[h];
    }
    float* orow = out + (size_t)r * 768 + lane * 12;
    *(float4*)(orow)     = make_float4(o[0], o[1], o[2],  o[3]);
    *(float4*)(orow + 4) = make_float4(o[4], o[5], o[6],  o[7]);
    *(float4*)(orow + 8) = make_float4(o[8], o[9], o[10], o[11]);
}

extern "C" void kernel_launch(void* const* d_in, const int* in_sizes, int n_in,
                              void* d_out, int out_size, void* d_ws, size_t ws_size,
                              hipStream_t stream)
{
    const float* x      = (const float*)d_in[0];
    const float* E      = (const float*)d_in[1];
    const int*   mask   = (const int*)d_in[2];
    const float* W1     = (const float*)d_in[3];
    const float* b1     = (const float*)d_in[4];
    const float* W2     = (const float*)d_in[5];
    const float* b2     = (const float*)d_in[6];
    const float* attn_W = (const float*)d_in[7];
    const float* gamma  = (const float*)d_in[8];
    const float* beta   = (const float*)d_in[9];
    float* out = (float*)d_out;

    const int BS = 8192, H = 768, M1 = 40960, KP = 256;

    char* p = (char*)d_ws;
    auto alloc = [&](size_t bytes) { char* q = p; p += (bytes + 255) & ~(size_t)255; return q; };
    __hip_bfloat16* xb    = (__hip_bfloat16*)alloc((size_t)BS * H * 2);    // 12.58 MB
    __hip_bfloat16* W2b   = (__hip_bfloat16*)alloc((size_t)H * H * 2);
    __hip_bfloat16* W2Tb  = (__hip_bfloat16*)alloc((size_t)H * H * 2);
    __hip_bfloat16* attnb = (__hip_bfloat16*)alloc((size_t)H * H * 2);
    __hip_bfloat16* Ctb   = (__hip_bfloat16*)alloc((size_t)H * H * 2);
    __hip_bfloat16* W1Tb  = (__hip_bfloat16*)alloc((size_t)H * KP * 2);
    __hip_bfloat16* Tb    = (__hip_bfloat16*)alloc((size_t)M1 * H * 2);    // 62.92 MB
    __hip_bfloat16* Eb    = (__hip_bfloat16*)alloc((size_t)M1 * KP * 2);   // 20.97 MB
    float* Hb = (float*)Tb;              // alias: Tb dead after attn
    __hip_bfloat16* Pb = Eb;             // alias: Eb dead after T-GEMM
    __hip_bfloat16* Sb = Pb;             // alias: same-wave read-then-write

    // --- all prep in one launch: 6144+576+576 cvt, 10240 padE, 192+576 transpose
    prep_kernel<<<18304, 256, 0, stream>>>(x, xb, W2, W2b, attn_W, attnb,
                                           E, Eb, W1, W1Tb, W2Tb);

    // T = tanh(Eb @ W1 + b1) [1920 blocks, swizzled, KREAL=224 tail-skip]
    //   + Ct = W2 @ attn_W^T [36 blocks] fused in one launch
    tct_kernel<<<1956, 256, 0, stream>>>(Eb, W1Tb, b1, Tb, W2b, attnb, Ctb);

    // P = x @ C   (384 blocks, XCD-swizzled)
    mfma_gemm<false, false, false, true, 768, 768, 6><<<384, 256, 0, stream>>>(
        xb, Ctb, nullptr, nullptr, Pb);
    // attention -> S
    attn_kernel<<<BS / 4, 256, 0, stream>>>(Tb, Pb, mask, Sb);
    // H = x + S @ W2 + b2
    mfma_gemm<true, false, true, false, 768, 768, 6><<<384, 256, 0, stream>>>(
        Sb, W2Tb, b2, x, Hb);
    // out = LN(H)*gamma + beta
    ln_kernel<<<BS / 4, 256, 0, stream>>>(Hb, gamma, beta, out);
}